// Round 6
// baseline (1076.565 us; speedup 1.0000x reference)
//
#include <hip/hip_runtime.h>

typedef unsigned short u16;
typedef short short8 __attribute__((ext_vector_type(8)));
typedef float f32x4 __attribute__((ext_vector_type(4)));

#define LOG2E 1.44269504088896340736f

__device__ __forceinline__ u16 f2bf(float f) {
  unsigned u = __builtin_bit_cast(unsigned, f);
  u += 0x7fffu + ((u >> 16) & 1u);
  return (u16)(u >> 16);
}

__device__ __forceinline__ unsigned cvt_pk_bf16(float lo, float hi) {
  unsigned r;
  asm("v_cvt_pk_bf16_f32 %0, %1, %2" : "=v"(r) : "v"(lo), "v"(hi));
  return r;
}

__device__ __forceinline__ float fast_exp2(float x) {
#if __has_builtin(__builtin_amdgcn_exp2f)
  return __builtin_amdgcn_exp2f(x);
#else
  float r;
  asm("v_exp_f32 %0, %1" : "=v"(r) : "v"(x));
  return r;
#endif
}

// ---------------- kernel 1: x fp32 -> bf16 ----------------
__global__ __launch_bounds__(256) void k_convert_x(const float* __restrict__ x,
                                                   u16* __restrict__ xb) {
  int i = blockIdx.x * 256 + threadIdx.x;
  float4 v = ((const float4*)x)[i];
  ushort4 o;
  o.x = f2bf(v.x); o.y = f2bf(v.y); o.z = f2bf(v.z); o.w = f2bf(v.w);
  ((ushort4*)xb)[i] = o;
}

// ---------------- kernel 2: WcatT [640][512] bf16 ----------------
__global__ __launch_bounds__(256) void k_wcat(const float* __restrict__ Wq,
                                              const float* __restrict__ Wk,
                                              const float* __restrict__ Wv,
                                              const float* __restrict__ Wo,
                                              u16* __restrict__ wcatT) {
  __shared__ float wo8T[8 * 512];
  int bid = blockIdx.x, t = threadIdx.x;
  if (bid < 8) {
    for (int i = t; i < 8192; i += 256) {
      int j = bid * 16 + (i >> 9);
      int c = i & 511;
      float v = (j < 64) ? Wq[c * 64 + j] * (0.125f * LOG2E) : Wk[c * 64 + (j - 64)];
      wcatT[j * 512 + c] = f2bf(v);
    }
  } else {
    int j0 = (bid - 8) * 8;
    for (int i = t; i < 4096; i += 256) {
      int jj = i >> 9, kk = i & 511;
      wo8T[jj * 512 + kk] = Wo[kk * 512 + j0 + jj];
    }
    __syncthreads();
    for (int c = t; c < 512; c += 256) {
      const float4* wr = (const float4*)(Wv + c * 512);
      float acc[8] = {};
      for (int kk = 0; kk < 128; kk++) {
        float4 v = wr[kk];
#pragma unroll
        for (int jj = 0; jj < 8; jj++) {
          float4 wa = *(const float4*)&wo8T[jj * 512 + kk * 4];
          acc[jj] += v.x * wa.x + v.y * wa.y + v.z * wa.z + v.w * wa.w;
        }
      }
#pragma unroll
      for (int jj = 0; jj < 8; jj++)
        wcatT[(128 + j0 + jj) * 512 + c] = f2bf(acc[jj]);
    }
  }
}

// ---------------- kernel 3: QKV' GEMM [16384,512]@[512,640] ----------------
// q  [16384][64] bf16 row-major
// kf fragment layout: u16 idx = ((((b*64+kt)*4+kb)*2+sl)*16+fr)*32 + fg*8 + e
// vf fragment layout: u16 idx = ((((b*64+kt)*32+ct)*2+ks)*16+fr)*32 + fg*8 + h*4 + e
__global__ __launch_bounds__(256) void k_qkv(const u16* __restrict__ xb,
                                             const u16* __restrict__ wcatT,
                                             u16* __restrict__ q,
                                             u16* __restrict__ kf,
                                             u16* __restrict__ vf) {
  __shared__ alignas(16) u16 lds[16384];
  int tid = threadIdx.x;
  int w = tid >> 6, lane = tid & 63;
  int fr = lane & 15, fg = lane >> 4;
  int wm = w >> 1, wn = w & 1;
  int rowbase = blockIdx.y * 128;
  int jbase = blockIdx.x * 128;
  f32x4 acc[4][4] = {};

  for (int kb = 0; kb < 512; kb += 64) {
    __syncthreads();
#pragma unroll
    for (int n = 0; n < 4; n++) {
      int lin = n * 4096 + tid * 16;
      int row = lin >> 7;
      int src = (((lin >> 4) & 7) * 16) ^ ((row & 7) << 4);
      const char* ga = (const char*)(xb + (size_t)(rowbase + row) * 512 + kb) + src;
      __builtin_amdgcn_global_load_lds(
          (const __attribute__((address_space(1))) void*)ga,
          (__attribute__((address_space(3))) void*)((char*)lds + n * 4096 + (w << 10)),
          16, 0, 0);
    }
#pragma unroll
    for (int n = 0; n < 4; n++) {
      int lin = n * 4096 + tid * 16;
      int row = lin >> 7;
      int src = (((lin >> 4) & 7) * 16) ^ ((row & 7) << 4);
      const char* ga = (const char*)(wcatT + (size_t)(jbase + row) * 512 + kb) + src;
      __builtin_amdgcn_global_load_lds(
          (const __attribute__((address_space(1))) void*)ga,
          (__attribute__((address_space(3))) void*)((char*)lds + 16384 + n * 4096 + (w << 10)),
          16, 0, 0);
    }
    __syncthreads();
    short8 af[4][2], bfr[4][2];
#pragma unroll
    for (int mt = 0; mt < 4; mt++)
#pragma unroll
      for (int ks = 0; ks < 2; ks++) {
        int row = wm * 64 + mt * 16 + fr;
        int off = row * 128 + ((ks * 64 + fg * 16) ^ ((row & 7) << 4));
        af[mt][ks] = *(const short8*)((const char*)lds + off);
      }
#pragma unroll
    for (int nt = 0; nt < 4; nt++)
#pragma unroll
      for (int ks = 0; ks < 2; ks++) {
        int j = wn * 64 + nt * 16 + fr;
        int off = 16384 + j * 128 + ((ks * 64 + fg * 16) ^ ((j & 7) << 4));
        bfr[nt][ks] = *(const short8*)((const char*)lds + off);
      }
#pragma unroll
    for (int ks = 0; ks < 2; ks++)
#pragma unroll
      for (int mt = 0; mt < 4; mt++)
#pragma unroll
        for (int nt = 0; nt < 4; nt++)
          acc[mt][nt] = __builtin_amdgcn_mfma_f32_16x16x32_bf16(
              af[mt][ks], bfr[nt][ks], acc[mt][nt], 0, 0, 0);
  }

  if (jbase < 128) {
    // repack q (cols 0..63) and K (cols 64..127) through LDS -> coalesced stores
    __syncthreads();
    int base = wn ? 8192 : 0;
#pragma unroll
    for (int mt = 0; mt < 4; mt++)
#pragma unroll
      for (int nt = 0; nt < 4; nt++) {
        int dd = nt * 16 + fr;
#pragma unroll
        for (int ii = 0; ii < 4; ii++) {
          int rl = wm * 64 + mt * 16 + fg * 4 + ii;
          lds[base + rl * 64 + dd] = f2bf(acc[mt][nt][ii]);
        }
      }
    __syncthreads();
    // q dump: LDS [row][64] == q row-major
    size_t qoff = (size_t)rowbase * 64;
#pragma unroll
    for (int c = 0; c < 4; c++) {
      int ch = c * 256 + tid;
      *(uint4*)(q + qoff + ch * 8) = *(const uint4*)&lds[ch * 8];
    }
    // kf dump: linear fragment order; source [key][d] in LDS
    int bb = rowbase >> 12;
    int kt0 = (rowbase & 4095) >> 6;
#pragma unroll
    for (int c = 0; c < 4; c++) {
      int ch = c * 256 + tid;
      int ktl = ch >> 9, r = ch & 511;
      int kb2 = r >> 7, sl = (r >> 6) & 1, frp = (r >> 2) & 15, fgk = r & 3;
      int key = ktl * 64 + kb2 * 16 + frp;
      int d = sl * 32 + fgk * 8;
      uint4 v = *(const uint4*)&lds[8192 + key * 64 + d];
      *(uint4*)(kf + ((size_t)(bb * 64 + kt0 + ktl)) * 4096 + r * 8) = v;
    }
  } else {
    // vf fragment stores: 16B uint4, coalesced
    int bb = rowbase >> 12;
    int ktb = ((rowbase & 4095) >> 6) + wm;
    int cbase = (jbase - 128) + wn * 64;
#pragma unroll
    for (int nt = 0; nt < 4; nt++) {
      int c = cbase + nt * 16 + fr;
      int ct = c >> 4;
#pragma unroll
      for (int mp = 0; mp < 2; mp++) {
        uint4 u;
        u.x = cvt_pk_bf16(acc[2 * mp][nt][0], acc[2 * mp][nt][1]);
        u.y = cvt_pk_bf16(acc[2 * mp][nt][2], acc[2 * mp][nt][3]);
        u.z = cvt_pk_bf16(acc[2 * mp + 1][nt][0], acc[2 * mp + 1][nt][1]);
        u.w = cvt_pk_bf16(acc[2 * mp + 1][nt][2], acc[2 * mp + 1][nt][3]);
        size_t off16 = (((size_t)((bb * 64 + ktb) * 32 + ct) * 2 + mp) * 16 + fr) * 4 + fg;
        *(uint4*)((char*)vf + off16 * 16) = u;
      }
    }
  }
}

// ---------------- kernel 4: 1-wave-per-block flash attention ----------------
// 2048 blocks x 64 thr. Block = (batch, 32-row q-block, 128-col slice). No LDS,
// no barriers; up to 4 waves/SIMD co-resident for latency hiding.
__global__ __launch_bounds__(64, 4) void k_attn(const u16* __restrict__ q,
                                                const u16* __restrict__ kf,
                                                const u16* __restrict__ vf,
                                                const float* __restrict__ x,
                                                const float* __restrict__ gamma_p,
                                                float* __restrict__ out) {
  int bi = blockIdx.x;
  int xcd = bi & 7, b = xcd >> 1;
  int idx = bi >> 3;                                // 0..255 within XCD
  int w = idx & 3;
  int qt = (((idx >> 2) & 63) << 1) | (xcd & 1);    // bijective, 2 XCDs/batch
  int qbase = qt * 32;

  int lane = threadIdx.x;
  int fr = lane & 15, fg = lane >> 4;
  int c0 = w * 128;

  short8 qa[2][2];
#pragma unroll
  for (int rt = 0; rt < 2; rt++) {
    const u16* qp = q + ((size_t)((b << 12) + qbase + rt * 16 + fr)) * 64 + fg * 8;
    qa[rt][0] = *(const short8*)qp;
    qa[rt][1] = *(const short8*)(qp + 32);
  }

  f32x4 o[2][8] = {};
  float mR[2] = {-1e30f, -1e30f};
  float lsum[2] = {0.f, 0.f};
  const f32x4 zero4 = {};

  const char* kfb = (const char*)(kf + ((size_t)b << 18)) + fr * 64 + fg * 16;
  const char* vfb = (const char*)(vf + ((size_t)b << 21)) + (w * 8) * 2048 + fr * 64 + fg * 16;

#define LOADKC(DST, T)                                                       \
  {                                                                          \
    const char* kp_ = kfb + (size_t)(T) * 8192;                              \
    _Pragma("unroll") for (int kb_ = 0; kb_ < 4; kb_++)                      \
        _Pragma("unroll") for (int sl_ = 0; sl_ < 2; sl_++)                  \
            DST[kb_][sl_] = *(const short8*)(kp_ + kb_ * 2048 + sl_ * 1024); \
  }

#define BODY(T, KU, KP)                                                                   \
  {                                                                                       \
    const char* vp = vfb + (size_t)(T) * 65536;                                           \
    f32x4 s[2][4];                                                                        \
    _Pragma("unroll") for (int rt = 0; rt < 2; rt++)                                      \
        _Pragma("unroll") for (int kb = 0; kb < 4; kb++)                                  \
            s[rt][kb] = __builtin_amdgcn_mfma_f32_16x16x32_bf16(KU[kb][0], qa[rt][0],     \
                                                                zero4, 0, 0, 0);          \
    _Pragma("unroll") for (int rt = 0; rt < 2; rt++)                                      \
        _Pragma("unroll") for (int kb = 0; kb < 4; kb++)                                  \
            s[rt][kb] = __builtin_amdgcn_mfma_f32_16x16x32_bf16(KU[kb][1], qa[rt][1],     \
                                                                s[rt][kb], 0, 0, 0);      \
    LOADKC(KP, ((T) + 1) & 63);                                                           \
    short8 vaA[4][2];                                                                     \
    _Pragma("unroll") for (int nt = 0; nt < 4; nt++)                                      \
        _Pragma("unroll") for (int ks = 0; ks < 2; ks++)                                  \
            vaA[nt][ks] = *(const short8*)(vp + nt * 2048 + ks * 1024);                   \
    short8 pk[2][2];                                                                      \
    _Pragma("unroll") for (int rt = 0; rt < 2; rt++) {                                    \
      float t0 = fmaxf(fmaxf(s[rt][0][0], s[rt][0][1]), fmaxf(s[rt][0][2], s[rt][0][3])); \
      float t1 = fmaxf(fmaxf(s[rt][1][0], s[rt][1][1]), fmaxf(s[rt][1][2], s[rt][1][3])); \
      float t2 = fmaxf(fmaxf(s[rt][2][0], s[rt][2][1]), fmaxf(s[rt][2][2], s[rt][2][3])); \
      float t3 = fmaxf(fmaxf(s[rt][3][0], s[rt][3][1]), fmaxf(s[rt][3][2], s[rt][3][3])); \
      float tm = fmaxf(fmaxf(t0, t1), fmaxf(t2, t3));                                     \
      tm = fmaxf(tm, __shfl_xor(tm, 16));                                                 \
      tm = fmaxf(tm, __shfl_xor(tm, 32));                                                 \
      float m = mR[rt];                                                                   \
      if (__builtin_expect(__any(tm > m + 8.0f), 0)) {                                    \
        float mn = fmaxf(m, tm);                                                          \
        float cr = fast_exp2(m - mn);                                                     \
        _Pragma("unroll") for (int nt = 0; nt < 8; nt++)                                  \
            _Pragma("unroll") for (int ii = 0; ii < 4; ii++) o[rt][nt][ii] *= cr;         \
        lsum[rt] *= cr;                                                                   \
        m = mn;                                                                           \
        mR[rt] = mn;                                                                      \
      }                                                                                   \
      float p[4][4];                                                                      \
      _Pragma("unroll") for (int kb = 0; kb < 4; kb++)                                    \
          _Pragma("unroll") for (int ii = 0; ii < 4; ii++)                                \
              p[kb][ii] = fast_exp2(s[rt][kb][ii] - m);                                   \
      float u0 = (p[0][0] + p[0][1]) + (p[0][2] + p[0][3]);                               \
      float u1 = (p[1][0] + p[1][1]) + (p[1][2] + p[1][3]);                               \
      float u2 = (p[2][0] + p[2][1]) + (p[2][2] + p[2][3]);                               \
      float u3 = (p[3][0] + p[3][1]) + (p[3][2] + p[3][3]);                               \
      lsum[rt] += (u0 + u1) + (u2 + u3);                                                  \
      _Pragma("unroll") for (int ks = 0; ks < 2; ks++) {                                  \
        int4 pi;                                                                          \
        pi.x = (int)cvt_pk_bf16(p[2 * ks][0], p[2 * ks][1]);                              \
        pi.y = (int)cvt_pk_bf16(p[2 * ks][2], p[2 * ks][3]);                              \
        pi.z = (int)cvt_pk_bf16(p[2 * ks + 1][0], p[2 * ks + 1][1]);                      \
        pi.w = (int)cvt_pk_bf16(p[2 * ks + 1][2], p[2 * ks + 1][3]);                      \
        pk[rt][ks] = __builtin_bit_cast(short8, pi);                                      \
      }                                                                                   \
    }                                                                                     \
    short8 vaB[4][2];                                                                     \
    _Pragma("unroll") for (int nt = 0; nt < 4; nt++)                                      \
        _Pragma("unroll") for (int ks = 0; ks < 2; ks++)                                  \
            vaB[nt][ks] = *(const short8*)(vp + (nt + 4) * 2048 + ks * 1024);             \
    __builtin_amdgcn_s_setprio(1);                                                        \
    _Pragma("unroll") for (int nt = 0; nt < 4; nt++) {                                    \
      o[0][nt] = __builtin_amdgcn_mfma_f32_16x16x32_bf16(vaA[nt][0], pk[0][0], o[0][nt], 0, 0, 0); \
      o[0][nt] = __builtin_amdgcn_mfma_f32_16x16x32_bf16(vaA[nt][1], pk[0][1], o[0][nt], 0, 0, 0); \
      o[1][nt] = __builtin_amdgcn_mfma_f32_16x16x32_bf16(vaA[nt][0], pk[1][0], o[1][nt], 0, 0, 0); \
      o[1][nt] = __builtin_amdgcn_mfma_f32_16x16x32_bf16(vaA[nt][1], pk[1][1], o[1][nt], 0, 0, 0); \
    }                                                                                     \
    _Pragma("unroll") for (int nt = 0; nt < 4; nt++) {                                    \
      o[0][nt + 4] = __builtin_amdgcn_mfma_f32_16x16x32_bf16(vaB[nt][0], pk[0][0], o[0][nt + 4], 0, 0, 0); \
      o[0][nt + 4] = __builtin_amdgcn_mfma_f32_16x16x32_bf16(vaB[nt][1], pk[0][1], o[0][nt + 4], 0, 0, 0); \
      o[1][nt + 4] = __builtin_amdgcn_mfma_f32_16x16x32_bf16(vaB[nt][0], pk[1][0], o[1][nt + 4], 0, 0, 0); \
      o[1][nt + 4] = __builtin_amdgcn_mfma_f32_16x16x32_bf16(vaB[nt][1], pk[1][1], o[1][nt + 4], 0, 0, 0); \
    }                                                                                     \
    __builtin_amdgcn_s_setprio(0);                                                        \
  }

  short8 kcA[4][2], kcB[4][2];
  LOADKC(kcA, 0);
  for (int kt = 0; kt < 64; kt += 2) {
    BODY(kt, kcA, kcB);
    BODY(kt + 1, kcB, kcA);
  }

  // epilogue: reduce l across fg lanes, then out = gamma * O/l + x
  float g = gamma_p[0];
#pragma unroll
  for (int rt = 0; rt < 2; rt++) {
    float ts = lsum[rt];
    ts += __shfl_xor(ts, 16);
    ts += __shfl_xor(ts, 32);
    float il = __builtin_amdgcn_rcpf(ts);
    size_t row = (size_t)((b << 12) + qbase + rt * 16 + fr);
#pragma unroll
    for (int nt = 0; nt < 8; nt++) {
      size_t idxg = row * 512 + c0 + nt * 16 + fg * 4;
      float4 xo = *(const float4*)(x + idxg);
      float4 r;
      r.x = g * o[rt][nt][0] * il + xo.x;
      r.y = g * o[rt][nt][1] * il + xo.y;
      r.z = g * o[rt][nt][2] * il + xo.z;
      r.w = g * o[rt][nt][3] * il + xo.w;
      *(float4*)(out + idxg) = r;
    }
  }
#undef BODY
#undef LOADKC
}

extern "C" void kernel_launch(void* const* d_in, const int* in_sizes, int n_in,
                              void* d_out, int out_size, void* d_ws, size_t ws_size,
                              hipStream_t stream) {
  const float* x  = (const float*)d_in[0];
  const float* Wq = (const float*)d_in[1];
  const float* Wk = (const float*)d_in[2];
  const float* Wv = (const float*)d_in[3];
  const float* Wo = (const float*)d_in[4];
  const float* gm = (const float*)d_in[5];
  float* out = (float*)d_out;

  char* ws = (char*)d_ws;
  u16* xb    = (u16*)(ws);
  u16* wcatT = (u16*)(ws + 16777216);
  u16* q     = (u16*)(ws + 17432576);
  u16* kf    = (u16*)(ws + 19529728);
  u16* vf    = (u16*)(ws + 21626880);

  hipLaunchKernelGGL(k_convert_x, dim3(8192), dim3(256), 0, stream, x, xb);
  hipLaunchKernelGGL(k_wcat, dim3(72), dim3(256), 0, stream, Wq, Wk, Wv, Wo, wcatT);
  hipLaunchKernelGGL(k_qkv, dim3(5, 128), dim3(256), 0, stream, xb, wcatT, q, kf, vf);
  hipLaunchKernelGGL(k_attn, dim3(2048), dim3(64), 0, stream, q, kf, vf, x, gm, out);
}